// Round 1
// baseline (316.558 us; speedup 1.0000x reference)
//
#include <hip/hip_runtime.h>
#include <math.h>

// Problem constants (from reference): B=4, K=256, D=128, H=4, alpha=0.2
// leaky(s) = 0.6*s + 0.4*|s|  (exact identity for alpha=0.2)
// e_ij = 0.6*(a.L_i) + 0.6*(a.R_j) + sum_d (0.4 a_d)|Lp_i,d + R_j,d| + bias
// The per-i constant 0.6*(a.Lp_i) cancels in softmax -> dropped.

constexpr int Bc = 4, Kc = 256, Dc = 128, Hc = 4;
constexpr int Mc = Bc * Kc;            // 1024 flattened rows
constexpr int HMD = Hc * Mc * Dc;      // 524288 floats per ws plane

// ---------------------------------------------------------------------------
// K1: Lp[h][m][d] = x[m] @ W[h,:D] + lin_b[h]   ;  Rp[h][m][d] = x[m] @ W[h,D:]
// 64x64 tile, 256 threads, 4x4 per-thread reg blocking. 256 blocks.
// ---------------------------------------------------------------------------
__global__ __launch_bounds__(256) void k1_lr(const float* __restrict__ x,
                                             const float* __restrict__ W,
                                             const float* __restrict__ lin_b,
                                             float* __restrict__ Lp,
                                             float* __restrict__ Rp) {
    __shared__ float Xs[128][64];   // [k][m] 32KB
    __shared__ float Ws[128][64];   // [k][n] 32KB

    const int tid = threadIdx.x;
    const int bid = blockIdx.x;
    const int nt  = bid & 1;
    const int mt  = (bid >> 1) & 15;
    const int sel = (bid >> 5) & 1;
    const int h   = (bid >> 6) & 3;
    const int m0  = mt * 64;
    const int n0  = nt * 64;

    // stage X tile: lanes own rows (conflict-free LDS writes)
    {
        const int m_l = tid & 63, kq = tid >> 6;   // kq in 0..3
        #pragma unroll
        for (int c = 0; c < 8; ++c) {
            const int k0 = kq * 32 + c * 4;
            const float4 v = *(const float4*)&x[(m0 + m_l) * Dc + k0];
            Xs[k0 + 0][m_l] = v.x;
            Xs[k0 + 1][m_l] = v.y;
            Xs[k0 + 2][m_l] = v.z;
            Xs[k0 + 3][m_l] = v.w;
        }
    }
    // stage W tile: coalesced along n, conflict-free writes
    {
        const int n_l = tid & 63, kq = tid >> 6;
        const float* Wb = W + ((h * 2 + sel) * Dc) * Dc;   // rows k, cols d
        #pragma unroll
        for (int kk = 0; kk < 32; ++kk) {
            const int k = kq * 32 + kk;
            Ws[k][n_l] = Wb[k * Dc + (n0 + n_l)];
        }
    }
    __syncthreads();

    const int tx = tid & 15, ty = tid >> 4;
    float acc[4][4];
    #pragma unroll
    for (int r = 0; r < 4; ++r)
        #pragma unroll
        for (int c = 0; c < 4; ++c) acc[r][c] = 0.f;

    #pragma unroll 16
    for (int k = 0; k < 128; ++k) {
        const float4 xa = *(const float4*)&Xs[k][ty * 4];
        const float4 wb = *(const float4*)&Ws[k][tx * 4];
        acc[0][0] = fmaf(xa.x, wb.x, acc[0][0]);
        acc[0][1] = fmaf(xa.x, wb.y, acc[0][1]);
        acc[0][2] = fmaf(xa.x, wb.z, acc[0][2]);
        acc[0][3] = fmaf(xa.x, wb.w, acc[0][3]);
        acc[1][0] = fmaf(xa.y, wb.x, acc[1][0]);
        acc[1][1] = fmaf(xa.y, wb.y, acc[1][1]);
        acc[1][2] = fmaf(xa.y, wb.z, acc[1][2]);
        acc[1][3] = fmaf(xa.y, wb.w, acc[1][3]);
        acc[2][0] = fmaf(xa.z, wb.x, acc[2][0]);
        acc[2][1] = fmaf(xa.z, wb.y, acc[2][1]);
        acc[2][2] = fmaf(xa.z, wb.z, acc[2][2]);
        acc[2][3] = fmaf(xa.z, wb.w, acc[2][3]);
        acc[3][0] = fmaf(xa.w, wb.x, acc[3][0]);
        acc[3][1] = fmaf(xa.w, wb.y, acc[3][1]);
        acc[3][2] = fmaf(xa.w, wb.z, acc[3][2]);
        acc[3][3] = fmaf(xa.w, wb.w, acc[3][3]);
    }

    float lb[4] = {0.f, 0.f, 0.f, 0.f};
    if (sel == 0) {
        const float4 lv = *(const float4*)&lin_b[h * Dc + n0 + tx * 4];
        lb[0] = lv.x; lb[1] = lv.y; lb[2] = lv.z; lb[3] = lv.w;
    }
    float* dst = (sel == 0 ? Lp : Rp) + h * (Mc * Dc);
    #pragma unroll
    for (int r = 0; r < 4; ++r) {
        float4 o;
        o.x = acc[r][0] + lb[0];
        o.y = acc[r][1] + lb[1];
        o.z = acc[r][2] + lb[2];
        o.w = acc[r][3] + lb[3];
        *(float4*)&dst[(m0 + ty * 4 + r) * Dc + n0 + tx * 4] = o;
    }
}

// ---------------------------------------------------------------------------
// K2: fused scores + softmax + PV per (h, b, 8-row i-tile). 512 blocks.
// Each of 256 lanes holds one full R row (128 VGPRs). Lp + 0.4*a broadcast
// from LDS. Softmax distributed across lanes (lane owns j = tid).
// Writes per-head partial PV (scaled by 1/H) to ws.
// ---------------------------------------------------------------------------
__global__ __launch_bounds__(256) void k2_attn(const float* __restrict__ x,
                                               const float* __restrict__ a,
                                               const float* __restrict__ bias,
                                               const float* __restrict__ Lp,
                                               const float* __restrict__ Rp,
                                               float* __restrict__ part) {
    __shared__ float4 aa4_lds[32];        // 0.4 * a[h]
    __shared__ float4 lp4_lds[8 * 32];    // 8 i-rows x 128 d  (reused for PV combine)
    __shared__ float  p_lds[256 * 9];     // p[j][i], stride 9 breaks bank conflicts
    __shared__ float  red_m[4][8];
    __shared__ float  red_s[4][8];

    const int tid = threadIdx.x;
    const int bid = blockIdx.x;
    const int it  = bid & 31;
    const int b   = (bid >> 5) & 3;
    const int h   = (bid >> 7) & 3;
    const int i0  = it * 8;
    const int w   = tid >> 6;
    const int l   = tid & 63;
    const int j   = tid;                  // lane owns score column j

    if (tid < 32) {
        const float4 av = *(const float4*)&a[h * Dc + tid * 4];
        aa4_lds[tid] = make_float4(0.4f * av.x, 0.4f * av.y, 0.4f * av.z, 0.4f * av.w);
    }
    {
        const float4* Lp4 = (const float4*)(Lp + (h * Mc + b * Kc + i0) * Dc);
        lp4_lds[tid] = Lp4[tid];          // 8 rows * 32 float4
    }

    // R row into registers (statically indexed everywhere)
    float4 r4[32];
    {
        const float4* Rp4 = (const float4*)(Rp + (h * Mc + b * Kc + j) * Dc);
        #pragma unroll
        for (int q = 0; q < 32; ++q) r4[q] = Rp4[q];
    }
    __syncthreads();

    // 0.6 * (a . R_j)  computed as 1.5 * (0.4a . R_j)
    float ar = 0.f;
    #pragma unroll
    for (int q = 0; q < 32; ++q) {
        const float4 aa = aa4_lds[q];
        const float4 r  = r4[q];
        ar = fmaf(aa.x, r.x, ar);
        ar = fmaf(aa.y, r.y, ar);
        ar = fmaf(aa.z, r.z, ar);
        ar = fmaf(aa.w, r.w, ar);
    }
    const float ebase = 1.5f * ar;

    float acc[8];
    #pragma unroll
    for (int i = 0; i < 8; ++i) acc[i] = 0.f;

    #pragma unroll
    for (int q = 0; q < 32; ++q) {
        const float4 aa = aa4_lds[q];
        const float4 r  = r4[q];
        #pragma unroll
        for (int i = 0; i < 8; ++i) {
            const float4 lp = lp4_lds[i * 32 + q];
            acc[i] = fmaf(aa.x, __builtin_fabsf(lp.x + r.x), acc[i]);
            acc[i] = fmaf(aa.y, __builtin_fabsf(lp.y + r.y), acc[i]);
            acc[i] = fmaf(aa.z, __builtin_fabsf(lp.z + r.z), acc[i]);
            acc[i] = fmaf(aa.w, __builtin_fabsf(lp.w + r.w), acc[i]);
        }
    }

    float e[8];
    #pragma unroll
    for (int i = 0; i < 8; ++i)
        e[i] = ebase + acc[i] + bias[(h * Kc + i0 + i) * Kc + j];

    // ---- softmax over j (distributed: 64 lanes x 4 waves) ----
    #pragma unroll
    for (int i = 0; i < 8; ++i) {
        float m = e[i];
        #pragma unroll
        for (int off = 32; off > 0; off >>= 1) m = fmaxf(m, __shfl_xor(m, off, 64));
        if (l == 0) red_m[w][i] = m;
    }
    __syncthreads();

    float p[8];
    #pragma unroll
    for (int i = 0; i < 8; ++i) {
        const float m = fmaxf(fmaxf(red_m[0][i], red_m[1][i]),
                              fmaxf(red_m[2][i], red_m[3][i]));
        float pv = __expf(e[i] - m);
        p[i] = pv;
        float s = pv;
        #pragma unroll
        for (int off = 32; off > 0; off >>= 1) s += __shfl_xor(s, off, 64);
        if (l == 0) red_s[w][i] = s;
    }
    __syncthreads();

    #pragma unroll
    for (int i = 0; i < 8; ++i) {
        const float s = red_s[0][i] + red_s[1][i] + red_s[2][i] + red_s[3][i];
        p_lds[j * 9 + i] = p[i] * (0.25f / s);   // fold 1/H
    }
    __syncthreads();

    // ---- PV: out[i][d] = sum_j p[i][j] * x[b][j][d] ----
    const int d  = tid & 127;
    const int ig = tid >> 7;                 // j-half
    float oacc[8];
    #pragma unroll
    for (int i = 0; i < 8; ++i) oacc[i] = 0.f;
    const float* xb = x + (b * Kc) * Dc;
    #pragma unroll 4
    for (int jj0 = 0; jj0 < 128; ++jj0) {
        const int jj = ig * 128 + jj0;
        const float xv = xb[jj * Dc + d];
        #pragma unroll
        for (int i = 0; i < 8; ++i)
            oacc[i] = fmaf(p_lds[jj * 9 + i], xv, oacc[i]);
    }

    float* comb = (float*)lp4_lds;           // reuse 4KB as [8][128]
    if (ig == 1) {
        #pragma unroll
        for (int i = 0; i < 8; ++i) comb[i * 128 + d] = oacc[i];
    }
    __syncthreads();
    if (ig == 0) {
        float* pg = part + (h * Mc + b * Kc + i0) * Dc;
        #pragma unroll
        for (int i = 0; i < 8; ++i)
            pg[i * Dc + d] = oacc[i] + comb[i * 128 + d];
    }
}

// ---------------------------------------------------------------------------
// K3: out = sum over heads of partials (each already scaled by 1/H)
// ---------------------------------------------------------------------------
__global__ __launch_bounds__(256) void k3_reduce(const float* __restrict__ part,
                                                 float* __restrict__ out) {
    const int idx = blockIdx.x * 256 + threadIdx.x;   // float4 index, 32768 total
    const float4* p = (const float4*)part;
    const float4 s0 = p[idx];
    const float4 s1 = p[idx + 32768];
    const float4 s2 = p[idx + 65536];
    const float4 s3 = p[idx + 98304];
    float4 o;
    o.x = s0.x + s1.x + s2.x + s3.x;
    o.y = s0.y + s1.y + s2.y + s3.y;
    o.z = s0.z + s1.z + s2.z + s3.z;
    o.w = s0.w + s1.w + s2.w + s3.w;
    ((float4*)out)[idx] = o;
}

extern "C" void kernel_launch(void* const* d_in, const int* in_sizes, int n_in,
                              void* d_out, int out_size, void* d_ws, size_t ws_size,
                              hipStream_t stream) {
    const float* x     = (const float*)d_in[0];
    const float* W     = (const float*)d_in[1];
    const float* lin_b = (const float*)d_in[2];
    const float* a     = (const float*)d_in[3];
    const float* bias  = (const float*)d_in[4];
    float* out = (float*)d_out;

    float* Lp   = (float*)d_ws;            // [H][M][D]
    float* Rp   = Lp + HMD;                // [H][M][D]
    float* part = Rp + HMD;                // [H][M][D]

    k1_lr<<<256, 256, 0, stream>>>(x, W, lin_b, Lp, Rp);
    k2_attn<<<512, 256, 0, stream>>>(x, a, bias, Lp, Rp, part);
    k3_reduce<<<128, 256, 0, stream>>>(part, out);
}

// Round 2
// 43.417 us; speedup vs baseline: 7.2911x; 7.2911x over previous
//
#include <hip/hip_runtime.h>
#include <math.h>

// B=4, K=256, D=128, H=4, alpha=0.2
// leaky(s) = 0.6*s + 0.4*|s|  (exact for alpha=0.2)
// e_ij = [0.6*(a.Lp_i) cancels in softmax] + 0.6*(a.R_j) + sum_d (0.4 a_d)|Lp_id + R_jd| + bias_ij
constexpr int Kc = 256, Dc = 128, Mc = 1024;    // Mc = B*K
constexpr int HMD = 4 * Mc * Dc;                // 524288 floats per ws plane

// ---------------------------------------------------------------------------
// K1 (256 blocks, 256 thr): 64x64-tile fp32 GEMM, 4x4 reg blocking.
//   bid <  128 : Lp[h][m][d] = x@W_src + lin_b          (native layout)
//   bid >= 128 : Rt[(h*4+b)][d][j] = (x@W_dst)^T        (transposed via role swap)
//                + ebase partials eb[(h*4+b)*2+dt][j] = 1.5 * sum_{d in half} 0.4*a_d*R_jd
// ---------------------------------------------------------------------------
__global__ __launch_bounds__(256) void k1(const float* __restrict__ x,
                                          const float* __restrict__ W,
                                          const float* __restrict__ lin_b,
                                          const float* __restrict__ a,
                                          float* __restrict__ Lp,
                                          float* __restrict__ Rt,
                                          float* __restrict__ eb) {
    __shared__ float As[128][64];   // [k][m-role]
    __shared__ float Bs[128][64];   // [k][n-role]
    __shared__ float red[4][16][4];

    const int tid = threadIdx.x;
    const int bid = blockIdx.x;
    const int tx = tid & 15, ty = tid >> 4;
    const bool isL = (bid < 128);

    // ---- decode + stage ----
    int h, b, m0, n0, dt;
    if (isL) {
        const int nt = bid & 1, mt = (bid >> 1) & 15;
        h = (bid >> 5) & 3;
        m0 = mt * 64; n0 = nt * 64; b = 0; dt = 0;
        // As[k][m_l] = x[m0+m_l][k]
        {
            const int m_l = tid & 63, kq = tid >> 6;
            #pragma unroll
            for (int c = 0; c < 8; ++c) {
                const int k0 = kq * 32 + c * 4;
                const float4 v = *(const float4*)&x[(m0 + m_l) * Dc + k0];
                As[k0 + 0][m_l] = v.x; As[k0 + 1][m_l] = v.y;
                As[k0 + 2][m_l] = v.z; As[k0 + 3][m_l] = v.w;
            }
        }
        // Bs[k][n_l] = W_src[k][n0+n_l]
        {
            const int n_l = tid & 63, kq = tid >> 6;
            const float* Wb = W + (h * 2) * Dc * Dc;
            #pragma unroll
            for (int kk = 0; kk < 32; ++kk) {
                const int k = kq * 32 + kk;
                Bs[k][n_l] = Wb[k * Dc + n0 + n_l];
            }
        }
    } else {
        const int r_ = bid - 128;
        const int jt = r_ & 3;
        dt = (r_ >> 2) & 1;
        b  = (r_ >> 3) & 3;
        h  = (r_ >> 5) & 3;
        m0 = dt * 64;          // m-role = d
        n0 = jt * 64;          // n-role = j
        // As[k][d_l] = W_dst[k][d0+d_l]
        {
            const int d_l = tid & 63, kq = tid >> 6;
            const float* Wb = W + ((h * 2 + 1) * Dc) * Dc;
            #pragma unroll
            for (int kk = 0; kk < 32; ++kk) {
                const int k = kq * 32 + kk;
                As[k][d_l] = Wb[k * Dc + m0 + d_l];
            }
        }
        // Bs[k][j_l] = x[b*256 + j0 + j_l][k]
        {
            const int j_l = tid & 63, kq = tid >> 6;
            #pragma unroll
            for (int c = 0; c < 8; ++c) {
                const int k0 = kq * 32 + c * 4;
                const float4 v = *(const float4*)&x[(b * Kc + n0 + j_l) * Dc + k0];
                Bs[k0 + 0][j_l] = v.x; Bs[k0 + 1][j_l] = v.y;
                Bs[k0 + 2][j_l] = v.z; Bs[k0 + 3][j_l] = v.w;
            }
        }
    }
    __syncthreads();

    // ---- shared 4x4 k-loop ----
    float acc[4][4];
    #pragma unroll
    for (int r = 0; r < 4; ++r)
        #pragma unroll
        for (int c = 0; c < 4; ++c) acc[r][c] = 0.f;

    #pragma unroll 16
    for (int k = 0; k < 128; ++k) {
        const float4 xa = *(const float4*)&As[k][ty * 4];
        const float4 wb = *(const float4*)&Bs[k][tx * 4];
        acc[0][0] = fmaf(xa.x, wb.x, acc[0][0]);
        acc[0][1] = fmaf(xa.x, wb.y, acc[0][1]);
        acc[0][2] = fmaf(xa.x, wb.z, acc[0][2]);
        acc[0][3] = fmaf(xa.x, wb.w, acc[0][3]);
        acc[1][0] = fmaf(xa.y, wb.x, acc[1][0]);
        acc[1][1] = fmaf(xa.y, wb.y, acc[1][1]);
        acc[1][2] = fmaf(xa.y, wb.z, acc[1][2]);
        acc[1][3] = fmaf(xa.y, wb.w, acc[1][3]);
        acc[2][0] = fmaf(xa.z, wb.x, acc[2][0]);
        acc[2][1] = fmaf(xa.z, wb.y, acc[2][1]);
        acc[2][2] = fmaf(xa.z, wb.z, acc[2][2]);
        acc[2][3] = fmaf(xa.z, wb.w, acc[2][3]);
        acc[3][0] = fmaf(xa.w, wb.x, acc[3][0]);
        acc[3][1] = fmaf(xa.w, wb.y, acc[3][1]);
        acc[3][2] = fmaf(xa.w, wb.z, acc[3][2]);
        acc[3][3] = fmaf(xa.w, wb.w, acc[3][3]);
    }

    if (isL) {
        const float4 lv = *(const float4*)&lin_b[h * Dc + n0 + tx * 4];
        float* dst = Lp + h * (Mc * Dc);
        #pragma unroll
        for (int r = 0; r < 4; ++r) {
            float4 o;
            o.x = acc[r][0] + lv.x; o.y = acc[r][1] + lv.y;
            o.z = acc[r][2] + lv.z; o.w = acc[r][3] + lv.w;
            *(float4*)&dst[(m0 + ty * 4 + r) * Dc + n0 + tx * 4] = o;
        }
    } else {
        // store Rt[(h*4+b)][d0+ty*4+r][j0 + tx*4 + c]  (coalesced along j)
        float* dst = Rt + ((h * 4 + b) * Dc + m0) * Kc + n0;
        #pragma unroll
        for (int r = 0; r < 4; ++r) {
            float4 o;
            o.x = acc[r][0]; o.y = acc[r][1]; o.z = acc[r][2]; o.w = acc[r][3];
            *(float4*)&dst[(ty * 4 + r) * Kc + tx * 4] = o;
        }
        // ebase partial: p4[c] = sum_r (0.4*a[d0+ty*4+r]) * acc[r][c]
        const float4 av = *(const float4*)&a[h * Dc + m0 + ty * 4];
        float p0 = 0.4f * (av.x * acc[0][0] + av.y * acc[1][0] + av.z * acc[2][0] + av.w * acc[3][0]);
        float p1 = 0.4f * (av.x * acc[0][1] + av.y * acc[1][1] + av.z * acc[2][1] + av.w * acc[3][1]);
        float p2 = 0.4f * (av.x * acc[0][2] + av.y * acc[1][2] + av.z * acc[2][2] + av.w * acc[3][2]);
        float p3 = 0.4f * (av.x * acc[0][3] + av.y * acc[1][3] + av.z * acc[2][3] + av.w * acc[3][3]);
        // reduce over the 4 ty values within each wave (tid bits 4..5)
        p0 += __shfl_xor(p0, 16, 64); p0 += __shfl_xor(p0, 32, 64);
        p1 += __shfl_xor(p1, 16, 64); p1 += __shfl_xor(p1, 32, 64);
        p2 += __shfl_xor(p2, 16, 64); p2 += __shfl_xor(p2, 32, 64);
        p3 += __shfl_xor(p3, 16, 64); p3 += __shfl_xor(p3, 32, 64);
        if (((tid >> 4) & 3) == 0) {
            const int w = tid >> 6;
            red[w][tx][0] = p0; red[w][tx][1] = p1;
            red[w][tx][2] = p2; red[w][tx][3] = p3;
        }
        __syncthreads();
        if (tid < 64) {
            const int txl = tid >> 2, c = tid & 3;
            const float v = red[0][txl][c] + red[1][txl][c] + red[2][txl][c] + red[3][txl][c];
            eb[((h * 4 + b) * 2 + dt) * Kc + n0 + tid] = 1.5f * v;
        }
    }
}

// ---------------------------------------------------------------------------
// K2 (512 blocks = h*b*32 i-tiles, 256 thr): e-tile 8x256 in registers
// (thread = 2i x 4j), wave = 2 i-rows -> shuffle softmax, then PV from LDS.
// ---------------------------------------------------------------------------
#define ESTEP(KK, AAC, LAC, LBC) do {                                     \
    const float4 rr = *(const float4*)&chunk[(k4 + (KK)) * Kc + tj * 4];  \
    acc00 = fmaf(AAC, __builtin_fabsf(LAC + rr.x), acc00);                \
    acc01 = fmaf(AAC, __builtin_fabsf(LAC + rr.y), acc01);                \
    acc02 = fmaf(AAC, __builtin_fabsf(LAC + rr.z), acc02);                \
    acc03 = fmaf(AAC, __builtin_fabsf(LAC + rr.w), acc03);                \
    acc10 = fmaf(AAC, __builtin_fabsf(LBC + rr.x), acc10);                \
    acc11 = fmaf(AAC, __builtin_fabsf(LBC + rr.y), acc11);                \
    acc12 = fmaf(AAC, __builtin_fabsf(LBC + rr.z), acc12);                \
    acc13 = fmaf(AAC, __builtin_fabsf(LBC + rr.w), acc13);                \
} while (0)

#define PVSTEP(KK, PC) do {                                               \
    const float4 xv = *(const float4*)&chunk[(j4 + (KK)) * Dc + td * 4];  \
    o0 = fmaf(PC, xv.x, o0); o1 = fmaf(PC, xv.y, o1);                     \
    o2 = fmaf(PC, xv.z, o2); o3 = fmaf(PC, xv.w, o3);                     \
} while (0)

__global__ __launch_bounds__(256) void k2(const float* __restrict__ x,
                                          const float* __restrict__ a,
                                          const float* __restrict__ bias,
                                          const float* __restrict__ Lp,
                                          const float* __restrict__ Rt,
                                          const float* __restrict__ eb,
                                          float* __restrict__ part) {
    __shared__ float chunk[32 * 256];   // 32KB: Rt d-chunks, then x j-chunks
    __shared__ float lp[8 * 128];       // Lp tile rows i0..i0+7
    __shared__ float aa[128];           // 0.4*a[h]
    __shared__ float pl[8 * 256];       // softmaxed P, i-major

    const int tid = threadIdx.x;
    const int bid = blockIdx.x;
    const int it = bid & 31, b = (bid >> 5) & 3, h = (bid >> 7) & 3;
    const int i0 = it * 8;
    const int ti = tid >> 6, tj = tid & 63;

    ((float4*)lp)[tid] = ((const float4*)(Lp + (h * Mc + b * Kc + i0) * Dc))[tid];
    if (tid < 32) {
        const float4 av = ((const float4*)(a + h * Dc))[tid];
        ((float4*)aa)[tid] = make_float4(0.4f * av.x, 0.4f * av.y, 0.4f * av.z, 0.4f * av.w);
    }

    float acc00 = 0, acc01 = 0, acc02 = 0, acc03 = 0;
    float acc10 = 0, acc11 = 0, acc12 = 0, acc13 = 0;
    const float4* RtB = (const float4*)(Rt + (h * 4 + b) * Dc * Kc);

    #pragma unroll 1
    for (int dt = 0; dt < 4; ++dt) {
        __syncthreads();
        const float4* src = RtB + dt * (32 * Kc / 4);
        #pragma unroll
        for (int q = 0; q < 8; ++q) ((float4*)chunk)[q * 256 + tid] = src[q * 256 + tid];
        __syncthreads();
        const float* lpa = lp + (ti * 2) * Dc + dt * 32;
        const float* lpb = lpa + Dc;
        const float* aad = aa + dt * 32;
        #pragma unroll
        for (int k4 = 0; k4 < 32; k4 += 4) {
            const float4 aaV = *(const float4*)&aad[k4];
            const float4 la  = *(const float4*)&lpa[k4];
            const float4 lb2 = *(const float4*)&lpb[k4];
            ESTEP(0, aaV.x, la.x, lb2.x);
            ESTEP(1, aaV.y, la.y, lb2.y);
            ESTEP(2, aaV.z, la.z, lb2.z);
            ESTEP(3, aaV.w, la.w, lb2.w);
        }
    }

    // ---- epilogue: e = acc + ebase_j + bias ----
    const int jb = tj * 4;
    const float4 e0 = *(const float4*)&eb[((h * 4 + b) * 2 + 0) * Kc + jb];
    const float4 e1 = *(const float4*)&eb[((h * 4 + b) * 2 + 1) * Kc + jb];
    const float4 bv0 = *(const float4*)&bias[(h * Kc + i0 + ti * 2 + 0) * Kc + jb];
    const float4 bv1 = *(const float4*)&bias[(h * Kc + i0 + ti * 2 + 1) * Kc + jb];
    float e00 = acc00 + e0.x + e1.x + bv0.x;
    float e01 = acc01 + e0.y + e1.y + bv0.y;
    float e02 = acc02 + e0.z + e1.z + bv0.z;
    float e03 = acc03 + e0.w + e1.w + bv0.w;
    float e10 = acc10 + e0.x + e1.x + bv1.x;
    float e11 = acc11 + e0.y + e1.y + bv1.y;
    float e12 = acc12 + e0.z + e1.z + bv1.z;
    float e13 = acc13 + e0.w + e1.w + bv1.w;

    // ---- wave softmax (wave == ti group: full j-row across 64 lanes) ----
    {
        float m = fmaxf(fmaxf(e00, e01), fmaxf(e02, e03));
        #pragma unroll
        for (int off = 1; off < 64; off <<= 1) m = fmaxf(m, __shfl_xor(m, off, 64));
        float p0 = __expf(e00 - m), p1 = __expf(e01 - m);
        float p2 = __expf(e02 - m), p3 = __expf(e03 - m);
        float s = p0 + p1 + p2 + p3;
        #pragma unroll
        for (int off = 1; off < 64; off <<= 1) s += __shfl_xor(s, off, 64);
        const float sc = 0.25f / s;   // fold 1/H
        *(float4*)&pl[(ti * 2 + 0) * Kc + jb] =
            make_float4(p0 * sc, p1 * sc, p2 * sc, p3 * sc);
    }
    {
        float m = fmaxf(fmaxf(e10, e11), fmaxf(e12, e13));
        #pragma unroll
        for (int off = 1; off < 64; off <<= 1) m = fmaxf(m, __shfl_xor(m, off, 64));
        float p0 = __expf(e10 - m), p1 = __expf(e11 - m);
        float p2 = __expf(e12 - m), p3 = __expf(e13 - m);
        float s = p0 + p1 + p2 + p3;
        #pragma unroll
        for (int off = 1; off < 64; off <<= 1) s += __shfl_xor(s, off, 64);
        const float sc = 0.25f / s;
        *(float4*)&pl[(ti * 2 + 1) * Kc + jb] =
            make_float4(p0 * sc, p1 * sc, p2 * sc, p3 * sc);
    }

    // ---- PV: out[i][d] = sum_j P[i][j] * x[b][j][d] ----
    float o0 = 0, o1 = 0, o2 = 0, o3 = 0;
    const int ig = tid >> 5;          // i row 0..7
    const int td = tid & 31;          // d quad
    __syncthreads();                  // pl visible; chunk free for reuse

    #pragma unroll 1
    for (int cd = 0; cd < 4; ++cd) {
        const float4* xs = (const float4*)(x + (b * Kc + cd * 64) * Dc);
        #pragma unroll
        for (int q = 0; q < 8; ++q) ((float4*)chunk)[q * 256 + tid] = xs[q * 256 + tid];
        __syncthreads();
        const float* pr = pl + ig * Kc + cd * 64;
        #pragma unroll
        for (int j4 = 0; j4 < 64; j4 += 4) {
            const float4 pv = *(const float4*)&pr[j4];
            PVSTEP(0, pv.x);
            PVSTEP(1, pv.y);
            PVSTEP(2, pv.z);
            PVSTEP(3, pv.w);
        }
        __syncthreads();
    }
    float* pg = part + (h * Mc + b * Kc + i0 + ig) * Dc + td * 4;
    *(float4*)pg = make_float4(o0, o1, o2, o3);
}

// ---------------------------------------------------------------------------
// K3: out = sum over heads of partials (each already scaled by 1/H)
// ---------------------------------------------------------------------------
__global__ __launch_bounds__(256) void k3(const float* __restrict__ part,
                                          float* __restrict__ out) {
    const int idx = blockIdx.x * 256 + threadIdx.x;   // float4 index, 32768 total
    const float4* p = (const float4*)part;
    const float4 s0 = p[idx];
    const float4 s1 = p[idx + 32768];
    const float4 s2 = p[idx + 65536];
    const float4 s3 = p[idx + 98304];
    float4 o;
    o.x = s0.x + s1.x + s2.x + s3.x;
    o.y = s0.y + s1.y + s2.y + s3.y;
    o.z = s0.z + s1.z + s2.z + s3.z;
    o.w = s0.w + s1.w + s2.w + s3.w;
    ((float4*)out)[idx] = o;
}

extern "C" void kernel_launch(void* const* d_in, const int* in_sizes, int n_in,
                              void* d_out, int out_size, void* d_ws, size_t ws_size,
                              hipStream_t stream) {
    const float* x     = (const float*)d_in[0];
    const float* W     = (const float*)d_in[1];
    const float* lin_b = (const float*)d_in[2];
    const float* a     = (const float*)d_in[3];
    const float* bias  = (const float*)d_in[4];
    float* out = (float*)d_out;

    float* Lp   = (float*)d_ws;            // [H][M][D]
    float* Rt   = Lp + HMD;                // [(H*B)][D][K]
    float* part = Rt + HMD;                // [H][M][D]
    float* eb   = out;                     // [(H*B)][2][K] = 8192 floats, scratch;
                                           // k3 fully overwrites out afterwards.

    k1<<<256, 256, 0, stream>>>(x, W, lin_b, a, Lp, Rt, eb);
    k2<<<512, 256, 0, stream>>>(x, a, bias, Lp, Rt, eb, part);
    k3<<<128, 256, 0, stream>>>(part, out);
}

// Round 3
// 34.898 us; speedup vs baseline: 9.0710x; 1.2441x over previous
//
#include <hip/hip_runtime.h>
#include <math.h>

// B=4, K=256, D=128, H=4, alpha=0.2
// leaky(s) = 0.6*s + 0.4*|s|  (exact for alpha=0.2)
// e_ij = [0.6*(a.Lp_i) cancels in softmax] + 0.6*(a.R_j) + sum_d (0.4 a_d)|Lp_id + R_jd| + bias_ij
constexpr int Kc = 256, Dc = 128, Mc = 1024;    // Mc = B*K
constexpr int HMD = 4 * Mc * Dc;                // 524288 floats per ws plane

// ---------------------------------------------------------------------------
// K1 (256 blocks, 256 thr): 64x64-tile fp32 GEMM, 4x4 reg blocking.
//   bid <  128 : Lp[h][m][d] = x@W_src + lin_b          (native layout)
//   bid >= 128 : Rt[(h*4+b)][d][j] = (x@W_dst)^T        (transposed via role swap)
//                + ebase partials eb[(h*4+b)*2+dt][j] = 1.5 * sum_{d in half} 0.4*a_d*R_jd
// ---------------------------------------------------------------------------
__global__ __launch_bounds__(256) void k1(const float* __restrict__ x,
                                          const float* __restrict__ W,
                                          const float* __restrict__ lin_b,
                                          const float* __restrict__ a,
                                          float* __restrict__ Lp,
                                          float* __restrict__ Rt,
                                          float* __restrict__ eb) {
    __shared__ float As[128][64];   // [k][m-role]
    __shared__ float Bs[128][64];   // [k][n-role]
    __shared__ float red[4][16][4];

    const int tid = threadIdx.x;
    const int bid = blockIdx.x;
    const int tx = tid & 15, ty = tid >> 4;
    const bool isL = (bid < 128);

    // ---- decode + stage ----
    int h, b, m0, n0, dt;
    if (isL) {
        const int nt = bid & 1, mt = (bid >> 1) & 15;
        h = (bid >> 5) & 3;
        m0 = mt * 64; n0 = nt * 64; b = 0; dt = 0;
        {
            const int m_l = tid & 63, kq = tid >> 6;
            #pragma unroll
            for (int c = 0; c < 8; ++c) {
                const int k0 = kq * 32 + c * 4;
                const float4 v = *(const float4*)&x[(m0 + m_l) * Dc + k0];
                As[k0 + 0][m_l] = v.x; As[k0 + 1][m_l] = v.y;
                As[k0 + 2][m_l] = v.z; As[k0 + 3][m_l] = v.w;
            }
        }
        {
            const int n_l = tid & 63, kq = tid >> 6;
            const float* Wb = W + (h * 2) * Dc * Dc;
            #pragma unroll
            for (int kk = 0; kk < 32; ++kk) {
                const int k = kq * 32 + kk;
                Bs[k][n_l] = Wb[k * Dc + n0 + n_l];
            }
        }
    } else {
        const int r_ = bid - 128;
        const int jt = r_ & 3;
        dt = (r_ >> 2) & 1;
        b  = (r_ >> 3) & 3;
        h  = (r_ >> 5) & 3;
        m0 = dt * 64;          // m-role = d
        n0 = jt * 64;          // n-role = j
        {
            const int d_l = tid & 63, kq = tid >> 6;
            const float* Wb = W + ((h * 2 + 1) * Dc) * Dc;
            #pragma unroll
            for (int kk = 0; kk < 32; ++kk) {
                const int k = kq * 32 + kk;
                As[k][d_l] = Wb[k * Dc + m0 + d_l];
            }
        }
        {
            const int j_l = tid & 63, kq = tid >> 6;
            #pragma unroll
            for (int c = 0; c < 8; ++c) {
                const int k0 = kq * 32 + c * 4;
                const float4 v = *(const float4*)&x[(b * Kc + n0 + j_l) * Dc + k0];
                Bs[k0 + 0][j_l] = v.x; Bs[k0 + 1][j_l] = v.y;
                Bs[k0 + 2][j_l] = v.z; Bs[k0 + 3][j_l] = v.w;
            }
        }
    }
    __syncthreads();

    float acc[4][4];
    #pragma unroll
    for (int r = 0; r < 4; ++r)
        #pragma unroll
        for (int c = 0; c < 4; ++c) acc[r][c] = 0.f;

    #pragma unroll 16
    for (int k = 0; k < 128; ++k) {
        const float4 xa = *(const float4*)&As[k][ty * 4];
        const float4 wb = *(const float4*)&Bs[k][tx * 4];
        acc[0][0] = fmaf(xa.x, wb.x, acc[0][0]);
        acc[0][1] = fmaf(xa.x, wb.y, acc[0][1]);
        acc[0][2] = fmaf(xa.x, wb.z, acc[0][2]);
        acc[0][3] = fmaf(xa.x, wb.w, acc[0][3]);
        acc[1][0] = fmaf(xa.y, wb.x, acc[1][0]);
        acc[1][1] = fmaf(xa.y, wb.y, acc[1][1]);
        acc[1][2] = fmaf(xa.y, wb.z, acc[1][2]);
        acc[1][3] = fmaf(xa.y, wb.w, acc[1][3]);
        acc[2][0] = fmaf(xa.z, wb.x, acc[2][0]);
        acc[2][1] = fmaf(xa.z, wb.y, acc[2][1]);
        acc[2][2] = fmaf(xa.z, wb.z, acc[2][2]);
        acc[2][3] = fmaf(xa.z, wb.w, acc[2][3]);
        acc[3][0] = fmaf(xa.w, wb.x, acc[3][0]);
        acc[3][1] = fmaf(xa.w, wb.y, acc[3][1]);
        acc[3][2] = fmaf(xa.w, wb.z, acc[3][2]);
        acc[3][3] = fmaf(xa.w, wb.w, acc[3][3]);
    }

    if (isL) {
        const float4 lv = *(const float4*)&lin_b[h * Dc + n0 + tx * 4];
        float* dst = Lp + h * (Mc * Dc);
        #pragma unroll
        for (int r = 0; r < 4; ++r) {
            float4 o;
            o.x = acc[r][0] + lv.x; o.y = acc[r][1] + lv.y;
            o.z = acc[r][2] + lv.z; o.w = acc[r][3] + lv.w;
            *(float4*)&dst[(m0 + ty * 4 + r) * Dc + n0 + tx * 4] = o;
        }
    } else {
        float* dst = Rt + ((h * 4 + b) * Dc + m0) * Kc + n0;
        #pragma unroll
        for (int r = 0; r < 4; ++r) {
            float4 o;
            o.x = acc[r][0]; o.y = acc[r][1]; o.z = acc[r][2]; o.w = acc[r][3];
            *(float4*)&dst[(ty * 4 + r) * Kc + tx * 4] = o;
        }
        const float4 av = *(const float4*)&a[h * Dc + m0 + ty * 4];
        float p0 = 0.4f * (av.x * acc[0][0] + av.y * acc[1][0] + av.z * acc[2][0] + av.w * acc[3][0]);
        float p1 = 0.4f * (av.x * acc[0][1] + av.y * acc[1][1] + av.z * acc[2][1] + av.w * acc[3][1]);
        float p2 = 0.4f * (av.x * acc[0][2] + av.y * acc[1][2] + av.z * acc[2][2] + av.w * acc[3][2]);
        float p3 = 0.4f * (av.x * acc[0][3] + av.y * acc[1][3] + av.z * acc[2][3] + av.w * acc[3][3]);
        p0 += __shfl_xor(p0, 16, 64); p0 += __shfl_xor(p0, 32, 64);
        p1 += __shfl_xor(p1, 16, 64); p1 += __shfl_xor(p1, 32, 64);
        p2 += __shfl_xor(p2, 16, 64); p2 += __shfl_xor(p2, 32, 64);
        p3 += __shfl_xor(p3, 16, 64); p3 += __shfl_xor(p3, 32, 64);
        if (((tid >> 4) & 3) == 0) {
            const int w = tid >> 6;
            red[w][tx][0] = p0; red[w][tx][1] = p1;
            red[w][tx][2] = p2; red[w][tx][3] = p3;
        }
        __syncthreads();
        if (tid < 64) {
            const int txl = tid >> 2, c = tid & 3;
            const float v = red[0][txl][c] + red[1][txl][c] + red[2][txl][c] + red[3][txl][c];
            eb[((h * 4 + b) * 2 + dt) * Kc + n0 + tid] = 1.5f * v;
        }
    }
}

// ---------------------------------------------------------------------------
// K2 rewrite: per (h,b,8-row i-tile), 512 blocks, 256 thr.
//   e-phase : thread (dq=tid>>6, j4=tid&63) owns acc[8i][4j] over a 32-d slice.
//             Rt read directly from global (coalesced b128, L2-hot);
//             lpT/aaT broadcast from LDS. Cross-wave dq-reduce via padded LDS.
//   softmax : thread (w, l) owns rows {2w,2w+1}, full j-row in one wave.
//   PV      : thread (jq=tid>>5, dd4=tid&31) register-blocks all 8 i;
//             x read directly from global; P broadcast from LDS; jq-reduce.
// ---------------------------------------------------------------------------
#define EROW(ACC, LPV)                                            \
    ACC.x = fmaf(aad, __builtin_fabsf((LPV) + rr.x), ACC.x);      \
    ACC.y = fmaf(aad, __builtin_fabsf((LPV) + rr.y), ACC.y);      \
    ACC.z = fmaf(aad, __builtin_fabsf((LPV) + rr.z), ACC.z);      \
    ACC.w = fmaf(aad, __builtin_fabsf((LPV) + rr.w), ACC.w);

__global__ __launch_bounds__(256) void k2(const float* __restrict__ x,
                                          const float* __restrict__ a,
                                          const float* __restrict__ bias,
                                          const float* __restrict__ Lp,
                                          const float* __restrict__ Rt,
                                          const float* __restrict__ eb,
                                          float* __restrict__ part) {
    __shared__ float red[256 * 36];   // 36 KB: e-reduce, then PV-reduce (stride 36 keeps b128 at BW floor)
    __shared__ float lpT[Dc * 8];     // [d][i] 4 KB
    __shared__ float pl[8 * Kc];      // [i][j] 8 KB
    __shared__ float aaT[Dc];         // 0.4*a[h]

    const int tid = threadIdx.x;
    const int bid0 = blockIdx.x;
    const int bid = (bid0 & 7) * 64 + (bid0 >> 3);   // XCD swizzle (512 %% 8 == 0): 2 hb-planes per XCD
    const int it = bid & 31, b = (bid >> 5) & 3, h = (bid >> 7) & 3;
    const int i0 = it * 8;
    const int hb = h * 4 + b;

    // ---- stage lpT (transpose 8x128 -> [d][i]) + aaT ----
    {
        const int d_s = tid & 127, ig = (tid >> 7) * 4;
        const float* lrow = Lp + (h * Mc + b * Kc + i0 + ig) * Dc + d_s;
        lpT[d_s * 8 + ig + 0] = lrow[0 * Dc];
        lpT[d_s * 8 + ig + 1] = lrow[1 * Dc];
        lpT[d_s * 8 + ig + 2] = lrow[2 * Dc];
        lpT[d_s * 8 + ig + 3] = lrow[3 * Dc];
    }
    if (tid < 32) {
        const float4 av = ((const float4*)(a + h * Dc))[tid];
        ((float4*)aaT)[tid] = make_float4(0.4f * av.x, 0.4f * av.y, 0.4f * av.z, 0.4f * av.w);
    }
    __syncthreads();

    // ---- e-phase ----
    const int dq = tid >> 6, j4 = tid & 63;
    float4 acc[8];
    #pragma unroll
    for (int i = 0; i < 8; ++i) acc[i] = make_float4(0.f, 0.f, 0.f, 0.f);

    {
        const float* rb = Rt + (hb * Dc + dq * 32) * Kc + j4 * 4;
        const float* lt = lpT + dq * 32 * 8;
        const float* at = aaT + dq * 32;
        #pragma unroll 8
        for (int dd = 0; dd < 32; ++dd) {
            const float4 rr = *(const float4*)(rb + dd * Kc);
            const float aad = at[dd];
            const float4 l0 = *(const float4*)(lt + dd * 8);
            const float4 l1 = *(const float4*)(lt + dd * 8 + 4);
            EROW(acc[0], l0.x); EROW(acc[1], l0.y);
            EROW(acc[2], l0.z); EROW(acc[3], l0.w);
            EROW(acc[4], l1.x); EROW(acc[5], l1.y);
            EROW(acc[6], l1.z); EROW(acc[7], l1.w);
        }
    }
    {
        float* myred = red + (dq * 64 + j4) * 36;
        #pragma unroll
        for (int i = 0; i < 8; ++i) *(float4*)&myred[i * 4] = acc[i];
    }
    __syncthreads();

    // ---- softmax: wave w owns rows 2w, 2w+1; lane l = j-quad ----
    const int w = tid >> 6, l = tid & 63;
    {
        const int r0 = 2 * w, r1 = 2 * w + 1;
        float4 e0 = make_float4(0.f, 0.f, 0.f, 0.f);
        float4 e1 = make_float4(0.f, 0.f, 0.f, 0.f);
        #pragma unroll
        for (int q = 0; q < 4; ++q) {
            const float* rp = red + (q * 64 + l) * 36;
            const float4 a0 = *(const float4*)&rp[r0 * 4];
            const float4 a1 = *(const float4*)&rp[r1 * 4];
            e0.x += a0.x; e0.y += a0.y; e0.z += a0.z; e0.w += a0.w;
            e1.x += a1.x; e1.y += a1.y; e1.z += a1.z; e1.w += a1.w;
        }
        const float4 eb0 = *(const float4*)&eb[(hb * 2 + 0) * Kc + l * 4];
        const float4 eb1 = *(const float4*)&eb[(hb * 2 + 1) * Kc + l * 4];
        const float jx = eb0.x + eb1.x, jy = eb0.y + eb1.y;
        const float jz = eb0.z + eb1.z, jw = eb0.w + eb1.w;
        const float4 bv0 = *(const float4*)&bias[(h * Kc + i0 + r0) * Kc + l * 4];
        const float4 bv1 = *(const float4*)&bias[(h * Kc + i0 + r1) * Kc + l * 4];
        e0.x += jx + bv0.x; e0.y += jy + bv0.y; e0.z += jz + bv0.z; e0.w += jw + bv0.w;
        e1.x += jx + bv1.x; e1.y += jy + bv1.y; e1.z += jz + bv1.z; e1.w += jw + bv1.w;

        {
            float m = fmaxf(fmaxf(e0.x, e0.y), fmaxf(e0.z, e0.w));
            #pragma unroll
            for (int off = 1; off < 64; off <<= 1) m = fmaxf(m, __shfl_xor(m, off, 64));
            const float p0 = __expf(e0.x - m), p1 = __expf(e0.y - m);
            const float p2 = __expf(e0.z - m), p3 = __expf(e0.w - m);
            float s = p0 + p1 + p2 + p3;
            #pragma unroll
            for (int off = 1; off < 64; off <<= 1) s += __shfl_xor(s, off, 64);
            const float sc = 0.25f / s;   // fold 1/H
            *(float4*)&pl[r0 * Kc + l * 4] = make_float4(p0 * sc, p1 * sc, p2 * sc, p3 * sc);
        }
        {
            float m = fmaxf(fmaxf(e1.x, e1.y), fmaxf(e1.z, e1.w));
            #pragma unroll
            for (int off = 1; off < 64; off <<= 1) m = fmaxf(m, __shfl_xor(m, off, 64));
            const float p0 = __expf(e1.x - m), p1 = __expf(e1.y - m);
            const float p2 = __expf(e1.z - m), p3 = __expf(e1.w - m);
            float s = p0 + p1 + p2 + p3;
            #pragma unroll
            for (int off = 1; off < 64; off <<= 1) s += __shfl_xor(s, off, 64);
            const float sc = 0.25f / s;
            *(float4*)&pl[r1 * Kc + l * 4] = make_float4(p0 * sc, p1 * sc, p2 * sc, p3 * sc);
        }
    }
    __syncthreads();

    // ---- PV: thread (jq, dd4) holds o[8i][4dd], j interleaved mod 8 ----
    const int jq = tid >> 5, dd4 = tid & 31;
    float4 o[8];
    #pragma unroll
    for (int i = 0; i < 8; ++i) o[i] = make_float4(0.f, 0.f, 0.f, 0.f);
    {
        const float* xb = x + (b * Kc) * Dc + dd4 * 4;
        #pragma unroll 4
        for (int jj = 0; jj < 32; ++jj) {
            const int j = jj * 8 + jq;
            const float4 xv = *(const float4*)(xb + j * Dc);
            #pragma unroll
            for (int i = 0; i < 8; ++i) {
                const float pv = pl[i * Kc + j];
                o[i].x = fmaf(pv, xv.x, o[i].x);
                o[i].y = fmaf(pv, xv.y, o[i].y);
                o[i].z = fmaf(pv, xv.z, o[i].z);
                o[i].w = fmaf(pv, xv.w, o[i].w);
            }
        }
    }
    {
        float* myred = red + (jq * 32 + dd4) * 36;
        #pragma unroll
        for (int i = 0; i < 8; ++i) *(float4*)&myred[i * 4] = o[i];
    }
    __syncthreads();

    {
        const int i_f = tid >> 5, dd_f = tid & 31;
        float4 s = make_float4(0.f, 0.f, 0.f, 0.f);
        #pragma unroll
        for (int q = 0; q < 8; ++q) {
            const float4 v = *(const float4*)&red[(q * 32 + dd_f) * 36 + i_f * 4];
            s.x += v.x; s.y += v.y; s.z += v.z; s.w += v.w;
        }
        *(float4*)&part[(h * Mc + b * Kc + i0 + i_f) * Dc + dd_f * 4] = s;
    }
}

// ---------------------------------------------------------------------------
// K3: out = sum over heads of partials (each already scaled by 1/H)
// ---------------------------------------------------------------------------
__global__ __launch_bounds__(256) void k3(const float* __restrict__ part,
                                          float* __restrict__ out) {
    const int idx = blockIdx.x * 256 + threadIdx.x;   // float4 index, 32768 total
    const float4* p = (const float4*)part;
    const float4 s0 = p[idx];
    const float4 s1 = p[idx + 32768];
    const float4 s2 = p[idx + 65536];
    const float4 s3 = p[idx + 98304];
    float4 o;
    o.x = s0.x + s1.x + s2.x + s3.x;
    o.y = s0.y + s1.y + s2.y + s3.y;
    o.z = s0.z + s1.z + s2.z + s3.z;
    o.w = s0.w + s1.w + s2.w + s3.w;
    ((float4*)out)[idx] = o;
}

extern "C" void kernel_launch(void* const* d_in, const int* in_sizes, int n_in,
                              void* d_out, int out_size, void* d_ws, size_t ws_size,
                              hipStream_t stream) {
    const float* x     = (const float*)d_in[0];
    const float* W     = (const float*)d_in[1];
    const float* lin_b = (const float*)d_in[2];
    const float* a     = (const float*)d_in[3];
    const float* bias  = (const float*)d_in[4];
    float* out = (float*)d_out;

    float* Lp   = (float*)d_ws;            // [H][M][D]
    float* Rt   = Lp + HMD;                // [(H*B)][D][K]
    float* part = Rt + HMD;                // [H][M][D]
    float* eb   = out;                     // [(H*B)][2][K] scratch; k3 overwrites out afterwards.

    k1<<<256, 256, 0, stream>>>(x, W, lin_b, a, Lp, Rt, eb);
    k2<<<512, 256, 0, stream>>>(x, a, bias, Lp, Rt, eb, part);
    k3<<<128, 256, 0, stream>>>(part, out);
}